// Round 1
// baseline (1899.321 us; speedup 1.0000x reference)
//
#include <hip/hip_runtime.h>
#include <hip/hip_bf16.h>
#include <math.h>

// RTM: key identities
//  - softmax over size-1 axis == 1  =>  q,k,Wq,Wk dead; newV == v
//  - scan carry is only cumV; token j state restarts from s0[:,j]
//    => per stage a:  V_a = LN1(T_a) @ Wv[a]^T   (all 4096 rows parallel)
//                     C_a = exclusive-prefix-sum over token axis of V_a
//                     T_{a+1} = MLP(LN2R(C_a @ Wo[a]^T + T_a))
// All GEMMs are NT (A row-major [r,k], W row-major [out,k]) -> m97 gemm_bt.

using bf16   = __bf16;
using bf16x8 = __attribute__((ext_vector_type(8))) __bf16;
using f32x4  = __attribute__((ext_vector_type(4))) float;

#define DEV __device__ __forceinline__

DEV void gload16(const bf16* g, bf16* l) {
  __builtin_amdgcn_global_load_lds(
      (const __attribute__((address_space(1))) unsigned int*)g,
      (__attribute__((address_space(3))) unsigned int*)l, 16, 0, 0);
}

enum { EPI_F32 = 0, EPI_PE = 1, EPI_RES = 2, EPI_BIAS_GELU = 3, EPI_BIAS = 4 };

// C[M=grid.x*128, N] = A[M,K] @ B[N,K]^T  (+ epilogue), bf16 in, fp32 acc.
template <int EPI>
__global__ __launch_bounds__(256) void gemm_bt(
    const bf16* __restrict__ A, const bf16* __restrict__ B,
    float* __restrict__ outF, bf16* __restrict__ outB,
    const float* __restrict__ aux, int K, int N)
{
  __shared__ bf16 As[128 * 32];
  __shared__ bf16 Bs[128 * 32];
  const int tid  = threadIdx.x;
  const int lane = tid & 63, wave = tid >> 6;
  const int m0 = blockIdx.x * 128, n0 = blockIdx.y * 128;

  // staging: 512 16B-chunks per tile, 2 per thread; chunk c -> row c>>2, kq c&3
  const bf16* aG0 = A + (size_t)(m0 + (tid >> 2)) * K + (tid & 3) * 8;
  const bf16* aG1 = aG0 + (size_t)64 * K;
  const bf16* bG0 = B + (size_t)(n0 + (tid >> 2)) * K + (tid & 3) * 8;
  const bf16* bG1 = bG0 + (size_t)64 * K;
  bf16* aL0 = &As[tid * 8];
  bf16* aL1 = &As[2048 + tid * 8];
  bf16* bL0 = &Bs[tid * 8];
  bf16* bL1 = &Bs[2048 + tid * 8];

  const int wr = (wave & 1) * 64, wc = (wave >> 1) * 64;
  const int lr = lane & 15, kb = lane >> 4;
  const bf16* apL = &As[(wr + lr) * 32 + kb * 8];
  const bf16* bpL = &Bs[(wc + lr) * 32 + kb * 8];

  f32x4 acc[4][4] = {};

  for (int k0 = 0; k0 < K; k0 += 32) {
    gload16(aG0 + k0, aL0);
    gload16(aG1 + k0, aL1);
    gload16(bG0 + k0, bL0);
    gload16(bG1 + k0, bL1);
    __syncthreads();
    bf16x8 af[4], bfv[4];
#pragma unroll
    for (int t = 0; t < 4; ++t) af[t] = *(const bf16x8*)(apL + t * 512);
#pragma unroll
    for (int t = 0; t < 4; ++t) bfv[t] = *(const bf16x8*)(bpL + t * 512);
#pragma unroll
    for (int mt = 0; mt < 4; ++mt)
#pragma unroll
      for (int nt = 0; nt < 4; ++nt)
        acc[mt][nt] = __builtin_amdgcn_mfma_f32_16x16x32_bf16(af[mt], bfv[nt], acc[mt][nt], 0, 0, 0);
    __syncthreads();
  }

  // C/D layout: col = lane&15, row = (lane>>4)*4 + reg  [verified m89/m91]
  const int row0 = m0 + wr + (lane >> 4) * 4;
  const int col0 = n0 + wc + lr;
#pragma unroll
  for (int mt = 0; mt < 4; ++mt) {
#pragma unroll
    for (int nt = 0; nt < 4; ++nt) {
      const int col = col0 + nt * 16;
      float bias = 0.f;
      if (EPI == EPI_BIAS_GELU || EPI == EPI_BIAS) bias = aux[col];
#pragma unroll
      for (int r = 0; r < 4; ++r) {
        const int row = row0 + mt * 16 + r;
        float v = acc[mt][nt][r];
        if (EPI == EPI_PE)  v += aux[(row & 255) * 768 + col];
        if (EPI == EPI_RES) v += aux[(size_t)row * N + col];
        if (EPI == EPI_BIAS) v += bias;
        if (EPI == EPI_BIAS_GELU) {
          v += bias;
          v = 0.5f * v * (1.f + erff(v * 0.70710678118654752f));
          outB[(size_t)row * N + col] = (bf16)v;
        } else {
          outF[(size_t)row * N + col] = v;
        }
      }
    }
  }
}

// One row (768) per block. MODE 0: out = LN(x)*g+b ; MODE 1: out = LN(x)*g+b + x
template <int MODE>
__global__ __launch_bounds__(256) void ln_kernel(
    const float* __restrict__ X, const float* __restrict__ g,
    const float* __restrict__ b, bf16* __restrict__ out)
{
  const int row = blockIdx.x, t = threadIdx.x;
  const float* x = X + (size_t)row * 768;
  float v0 = x[t], v1 = x[t + 256], v2 = x[t + 512];
  __shared__ float red[8];
  float s = v0 + v1 + v2;
#pragma unroll
  for (int o = 32; o >= 1; o >>= 1) s += __shfl_down(s, o);
  if ((t & 63) == 0) red[t >> 6] = s;
  __syncthreads();
  const float mu = (red[0] + red[1] + red[2] + red[3]) * (1.f / 768.f);
  const float d0 = v0 - mu, d1 = v1 - mu, d2 = v2 - mu;
  float q = d0 * d0 + d1 * d1 + d2 * d2;
#pragma unroll
  for (int o = 32; o >= 1; o >>= 1) q += __shfl_down(q, o);
  if ((t & 63) == 0) red[4 + (t >> 6)] = q;
  __syncthreads();
  const float var = (red[4] + red[5] + red[6] + red[7]) * (1.f / 768.f);
  const float rs = rsqrtf(var + 1e-5f);
  float y0 = d0 * rs * g[t] + b[t];
  float y1 = d1 * rs * g[t + 256] + b[t + 256];
  float y2 = d2 * rs * g[t + 512] + b[t + 512];
  if (MODE) { y0 += v0; y1 += v1; y2 += v2; }
  bf16* o = out + (size_t)row * 768;
  o[t] = (bf16)y0; o[t + 256] = (bf16)y1; o[t + 512] = (bf16)y2;
}

// Exclusive prefix-sum of V over token axis j (per n, per d), fp32.
// grid (16 n, 16 chunk, 3 dgrp), 16 tokens/chunk.
__global__ __launch_bounds__(256) void scan_partial(
    const float* __restrict__ V, float* __restrict__ Ps)
{
  const int n = blockIdx.x, ch = blockIdx.y, d = blockIdx.z * 256 + threadIdx.x;
  const float* base = V + ((size_t)(n * 256 + ch * 16)) * 768 + d;
  float s = 0.f;
#pragma unroll
  for (int j = 0; j < 16; ++j) s += base[(size_t)j * 768];
  Ps[(size_t)(n * 16 + ch) * 768 + d] = s;
}

__global__ __launch_bounds__(256) void scan_final(
    const float* __restrict__ V, const float* __restrict__ Ps, bf16* __restrict__ Cb)
{
  const int n = blockIdx.x, ch = blockIdx.y, d = blockIdx.z * 256 + threadIdx.x;
  float run = 0.f;
  for (int c = 0; c < ch; ++c) run += Ps[(size_t)(n * 16 + c) * 768 + d];
  const float* vb = V + ((size_t)(n * 256 + ch * 16)) * 768 + d;
  bf16* cb = Cb + ((size_t)(n * 256 + ch * 16)) * 768 + d;
#pragma unroll
  for (int j = 0; j < 16; ++j) {
    cb[(size_t)j * 768] = (bf16)run;
    run += vb[(size_t)j * 768];
  }
}

__global__ __launch_bounds__(256) void f32_to_bf16_k(
    const float* __restrict__ in, bf16* __restrict__ out, int n4)
{
  const int i = blockIdx.x * 256 + threadIdx.x;
  if (i >= n4) return;
  const float4 v = ((const float4*)in)[i];
  bf16 h[4] = {(bf16)v.x, (bf16)v.y, (bf16)v.z, (bf16)v.w};
  *(uint2*)(out + 4 * (size_t)i) = *(uint2*)h;
}

// pe[j, 2p] = sin(j / 10000^(4p/768)),  pe[j, 2p+1] = cos(...)
__global__ __launch_bounds__(256) void pe_kernel(float* __restrict__ PE)
{
  const int id = blockIdx.x * 256 + threadIdx.x;  // 256*384 total
  const int j = id / 384, p = id % 384;
  const double ang = (double)j * pow(10000.0, -4.0 * (double)p / 768.0);
  PE[(size_t)j * 768 + 2 * p]     = (float)sin(ang);
  PE[(size_t)j * 768 + 2 * p + 1] = (float)cos(ang);
}

extern "C" void kernel_launch(void* const* d_in, const int* in_sizes, int n_in,
                              void* d_out, int out_size, void* d_ws, size_t ws_size,
                              hipStream_t stream)
{
  const float* x      = (const float*)d_in[0];
  const float* weight = (const float*)d_in[1];
  const float* Wv     = (const float*)d_in[4];
  const float* Wo     = (const float*)d_in[5];
  const float* ln1g   = (const float*)d_in[6];
  const float* ln1b   = (const float*)d_in[7];
  const float* ln2g   = (const float*)d_in[8];
  const float* ln2b   = (const float*)d_in[9];
  const float* fc1w   = (const float*)d_in[10];
  const float* fc1b   = (const float*)d_in[11];
  const float* fc2w   = (const float*)d_in[12];
  const float* fc2b   = (const float*)d_in[13];
  float* out = (float*)d_out;

  char* p = (char*)d_ws;
  auto alloc = [&](size_t bytes) { char* r = p; p += (bytes + 255) & ~(size_t)255; return r; };
  bf16*  Wb_w  = (bf16*)alloc(589824ull * 2);
  bf16*  Wb_v  = (bf16*)alloc(5898240ull * 2);
  bf16*  Wb_o  = (bf16*)alloc(5898240ull * 2);
  bf16*  Wb_f1 = (bf16*)alloc(2359296ull * 2);
  bf16*  Wb_f2 = (bf16*)alloc(2359296ull * 2);
  bf16*  Xb    = (bf16*)alloc(3145728ull * 2);
  float* PEf   = (float*)alloc(196608ull * 4);
  float* T     = (float*)alloc(3145728ull * 4);
  bf16*  SN    = (bf16*)alloc(3145728ull * 2);   // LN1 out; reused as LN2R out
  float* V     = (float*)alloc(3145728ull * 4);  // V; reused as S1
  bf16*  Cb    = (bf16*)alloc(3145728ull * 2);
  bf16*  H     = (bf16*)alloc(12582912ull * 2);
  float* Ps    = (float*)alloc(196608ull * 4);

  auto cvt = [&](const float* src, bf16* dst, int n) {
    int n4 = n / 4;
    f32_to_bf16_k<<<(n4 + 255) / 256, 256, 0, stream>>>(src, dst, n4);
  };
  cvt(x, Xb, 3145728);
  cvt(weight, Wb_w, 589824);
  cvt(Wv, Wb_v, 5898240);
  cvt(Wo, Wb_o, 5898240);
  cvt(fc1w, Wb_f1, 2359296);
  cvt(fc2w, Wb_f2, 2359296);
  pe_kernel<<<384, 256, 0, stream>>>(PEf);

  // T0 = x @ weight^T + PE
  gemm_bt<EPI_PE><<<dim3(32, 6), 256, 0, stream>>>(Xb, Wb_w, T, nullptr, PEf, 768, 768);

  for (int a = 0; a < 10; ++a) {
    ln_kernel<0><<<4096, 256, 0, stream>>>(T, ln1g, ln1b, SN);
    gemm_bt<EPI_F32><<<dim3(32, 6), 256, 0, stream>>>(SN, Wb_v + (size_t)a * 589824, V, nullptr, nullptr, 768, 768);
    scan_partial<<<dim3(16, 16, 3), 256, 0, stream>>>(V, Ps);
    scan_final<<<dim3(16, 16, 3), 256, 0, stream>>>(V, Ps, Cb);
    // S1 = C @ Wo^T + T   (S1 aliases V; V is dead after scan_final)
    gemm_bt<EPI_RES><<<dim3(32, 6), 256, 0, stream>>>(Cb, Wb_o + (size_t)a * 589824, V, nullptr, T, 768, 768);
    ln_kernel<1><<<4096, 256, 0, stream>>>(V, ln2g, ln2b, SN);  // S2 = LN2(S1)+S1
    gemm_bt<EPI_BIAS_GELU><<<dim3(32, 24), 256, 0, stream>>>(SN, Wb_f1, nullptr, H, fc1b, 768, 3072);
    float* dst = (a == 9) ? out : T;
    gemm_bt<EPI_BIAS><<<dim3(32, 6), 256, 0, stream>>>(H, Wb_f2, dst, nullptr, fc2b, 3072, 768);
  }
  (void)in_sizes; (void)n_in; (void)out_size; (void)ws_size;
}

// Round 2
// 1526.147 us; speedup vs baseline: 1.2445x; 1.2445x over previous
//
#include <hip/hip_runtime.h>
#include <hip/hip_bf16.h>
#include <math.h>

// RTM: key identities
//  - softmax over size-1 axis == 1  =>  q,k,Wq,Wk dead; newV == v
//  - scan carry is only cumV; token j state restarts from s0[:,j]
//    => per stage a:  V_a = LN1(T_a) @ Wv[a]^T   (all 4096 rows parallel)
//                     C_a = exclusive-prefix-sum over token axis of V_a
//                     T_{a+1} = MLP(LN2R(C_a @ Wo[a]^T + T_a))
// All GEMMs are NT (A row-major [r,k], W row-major [out,k]).
// R2: 64x64 tiles everywhere (grid 768/3072 blocks -> ~8 blocks/CU latency
// hiding; R1's 192-block grids left 25% of CUs idle) + inline fast erf
// (library erff was ~100 instrs -> 27% VALUBusy on fc1).

using bf16   = __bf16;
using bf16x8 = __attribute__((ext_vector_type(8))) __bf16;
using f32x4  = __attribute__((ext_vector_type(4))) float;

#define DEV __device__ __forceinline__

DEV void gload16(const bf16* g, bf16* l) {
  __builtin_amdgcn_global_load_lds(
      (const __attribute__((address_space(1))) unsigned int*)g,
      (__attribute__((address_space(3))) unsigned int*)l, 16, 0, 0);
}

// GELU with Abramowitz-Stegun 7.1.26 erf (abs err 1.5e-7; << bf16 rounding).
DEV float gelu_f(float x) {
  const float y  = x * 0.70710678118654752f;
  const float ay = fabsf(y);
  const float t  = __builtin_amdgcn_rcpf(__builtin_fmaf(0.3275911f, ay, 1.0f));
  float p = __builtin_fmaf(1.061405429f, t, -1.453152027f);
  p = __builtin_fmaf(p, t, 1.421413741f);
  p = __builtin_fmaf(p, t, -0.284496736f);
  p = __builtin_fmaf(p, t, 0.254829592f);
  p = p * t;
  const float e = __expf(-ay * ay);
  float er = __builtin_fmaf(-p, e, 1.0f);
  er = __builtin_copysignf(er, y);
  return 0.5f * x * (1.0f + er);
}

enum { EPI_F32 = 0, EPI_PE = 1, EPI_RES = 2, EPI_BIAS_GELU = 3, EPI_BIAS = 4 };

// C[M,N] = A[M,K] @ B[N,K]^T (+ epilogue), bf16 in, fp32 acc.
// Tile BM x BN, BK=32, 256 threads (4 waves, 2x2 wave grid of (BM/2)x(BN/2)).
template <int BM, int BN, int EPI>
__global__ __launch_bounds__(256) void gemm_bt(
    const bf16* __restrict__ A, const bf16* __restrict__ B,
    float* __restrict__ outF, bf16* __restrict__ outB,
    const float* __restrict__ aux, int K, int N)
{
  __shared__ bf16 As[BM * 32];
  __shared__ bf16 Bs[BN * 32];
  const int tid  = threadIdx.x;
  const int lane = tid & 63, wave = tid >> 6;
  const int m0 = blockIdx.x * BM, n0 = blockIdx.y * BN;

  constexpr int AC = BM / 64, BC = BN / 64;   // 16B staging chunks per thread
  const bf16* aG[AC]; const bf16* bG[BC];
  bf16* aL[AC]; bf16* bL[BC];
#pragma unroll
  for (int i = 0; i < AC; ++i) {
    aG[i] = A + (size_t)(m0 + i * 64 + (tid >> 2)) * K + (tid & 3) * 8;
    aL[i] = &As[i * 2048 + tid * 8];
  }
#pragma unroll
  for (int i = 0; i < BC; ++i) {
    bG[i] = B + (size_t)(n0 + i * 64 + (tid >> 2)) * K + (tid & 3) * 8;
    bL[i] = &Bs[i * 2048 + tid * 8];
  }

  const int wr = (wave & 1) * (BM / 2), wc = (wave >> 1) * (BN / 2);
  const int lr = lane & 15, kb = lane >> 4;
  const bf16* apL = &As[(wr + lr) * 32 + kb * 8];
  const bf16* bpL = &Bs[(wc + lr) * 32 + kb * 8];

  constexpr int MT = BM / 32, NT = BN / 32;   // 16-row frags per wave
  f32x4 acc[MT][NT] = {};

  for (int k0 = 0; k0 < K; k0 += 32) {
#pragma unroll
    for (int i = 0; i < AC; ++i) gload16(aG[i] + k0, aL[i]);
#pragma unroll
    for (int i = 0; i < BC; ++i) gload16(bG[i] + k0, bL[i]);
    __syncthreads();
    bf16x8 af[MT], bfv[NT];
#pragma unroll
    for (int t = 0; t < MT; ++t) af[t] = *(const bf16x8*)(apL + t * 512);
#pragma unroll
    for (int t = 0; t < NT; ++t) bfv[t] = *(const bf16x8*)(bpL + t * 512);
#pragma unroll
    for (int mt = 0; mt < MT; ++mt)
#pragma unroll
      for (int nt = 0; nt < NT; ++nt)
        acc[mt][nt] = __builtin_amdgcn_mfma_f32_16x16x32_bf16(af[mt], bfv[nt], acc[mt][nt], 0, 0, 0);
    __syncthreads();
  }

  // C/D layout: col = lane&15, row = (lane>>4)*4 + reg  [verified m89/m91]
  const int row0 = m0 + wr + (lane >> 4) * 4;
  const int col0 = n0 + wc + lr;
#pragma unroll
  for (int mt = 0; mt < MT; ++mt) {
#pragma unroll
    for (int nt = 0; nt < NT; ++nt) {
      const int col = col0 + nt * 16;
      float bias = 0.f;
      if (EPI == EPI_BIAS_GELU || EPI == EPI_BIAS) bias = aux[col];
#pragma unroll
      for (int r = 0; r < 4; ++r) {
        const int row = row0 + mt * 16 + r;
        float v = acc[mt][nt][r];
        if (EPI == EPI_PE)  v += aux[(row & 255) * 768 + col];
        if (EPI == EPI_RES) v += aux[(size_t)row * N + col];
        if (EPI == EPI_BIAS) v += bias;
        if (EPI == EPI_BIAS_GELU) {
          v = gelu_f(v + bias);
          outB[(size_t)row * N + col] = (bf16)v;
        } else {
          outF[(size_t)row * N + col] = v;
        }
      }
    }
  }
}

// One row (768) per block. MODE 0: out = LN(x)*g+b ; MODE 1: out = LN(x)*g+b + x
template <int MODE>
__global__ __launch_bounds__(256) void ln_kernel(
    const float* __restrict__ X, const float* __restrict__ g,
    const float* __restrict__ b, bf16* __restrict__ out)
{
  const int row = blockIdx.x, t = threadIdx.x;
  const float* x = X + (size_t)row * 768;
  float v0 = x[t], v1 = x[t + 256], v2 = x[t + 512];
  __shared__ float red[8];
  float s = v0 + v1 + v2;
#pragma unroll
  for (int o = 32; o >= 1; o >>= 1) s += __shfl_down(s, o);
  if ((t & 63) == 0) red[t >> 6] = s;
  __syncthreads();
  const float mu = (red[0] + red[1] + red[2] + red[3]) * (1.f / 768.f);
  const float d0 = v0 - mu, d1 = v1 - mu, d2 = v2 - mu;
  float q = d0 * d0 + d1 * d1 + d2 * d2;
#pragma unroll
  for (int o = 32; o >= 1; o >>= 1) q += __shfl_down(q, o);
  if ((t & 63) == 0) red[4 + (t >> 6)] = q;
  __syncthreads();
  const float var = (red[4] + red[5] + red[6] + red[7]) * (1.f / 768.f);
  const float rs = rsqrtf(var + 1e-5f);
  float y0 = d0 * rs * g[t] + b[t];
  float y1 = d1 * rs * g[t + 256] + b[t + 256];
  float y2 = d2 * rs * g[t + 512] + b[t + 512];
  if (MODE) { y0 += v0; y1 += v1; y2 += v2; }
  bf16* o = out + (size_t)row * 768;
  o[t] = (bf16)y0; o[t + 256] = (bf16)y1; o[t + 512] = (bf16)y2;
}

// Exclusive prefix-sum of V over token axis j (per n, per d), fp32.
__global__ __launch_bounds__(256) void scan_partial(
    const float* __restrict__ V, float* __restrict__ Ps)
{
  const int n = blockIdx.x, ch = blockIdx.y, d = blockIdx.z * 256 + threadIdx.x;
  const float* base = V + ((size_t)(n * 256 + ch * 16)) * 768 + d;
  float s = 0.f;
#pragma unroll
  for (int j = 0; j < 16; ++j) s += base[(size_t)j * 768];
  Ps[(size_t)(n * 16 + ch) * 768 + d] = s;
}

__global__ __launch_bounds__(256) void scan_final(
    const float* __restrict__ V, const float* __restrict__ Ps, bf16* __restrict__ Cb)
{
  const int n = blockIdx.x, ch = blockIdx.y, d = blockIdx.z * 256 + threadIdx.x;
  float run = 0.f;
  for (int c = 0; c < ch; ++c) run += Ps[(size_t)(n * 16 + c) * 768 + d];
  const float* vb = V + ((size_t)(n * 256 + ch * 16)) * 768 + d;
  bf16* cb = Cb + ((size_t)(n * 256 + ch * 16)) * 768 + d;
#pragma unroll
  for (int j = 0; j < 16; ++j) {
    cb[(size_t)j * 768] = (bf16)run;
    run += vb[(size_t)j * 768];
  }
}

__global__ __launch_bounds__(256) void f32_to_bf16_k(
    const float* __restrict__ in, bf16* __restrict__ out, int n4)
{
  const int i = blockIdx.x * 256 + threadIdx.x;
  if (i >= n4) return;
  const float4 v = ((const float4*)in)[i];
  bf16 h[4] = {(bf16)v.x, (bf16)v.y, (bf16)v.z, (bf16)v.w};
  *(uint2*)(out + 4 * (size_t)i) = *(uint2*)h;
}

// pe[j, 2p] = sin(j / 10000^(4p/768)),  pe[j, 2p+1] = cos(...)
__global__ __launch_bounds__(256) void pe_kernel(float* __restrict__ PE)
{
  const int id = blockIdx.x * 256 + threadIdx.x;  // 256*384 total
  const int j = id / 384, p = id % 384;
  const double ang = (double)j * pow(10000.0, -4.0 * (double)p / 768.0);
  PE[(size_t)j * 768 + 2 * p]     = (float)sin(ang);
  PE[(size_t)j * 768 + 2 * p + 1] = (float)cos(ang);
}

extern "C" void kernel_launch(void* const* d_in, const int* in_sizes, int n_in,
                              void* d_out, int out_size, void* d_ws, size_t ws_size,
                              hipStream_t stream)
{
  const float* x      = (const float*)d_in[0];
  const float* weight = (const float*)d_in[1];
  const float* Wv     = (const float*)d_in[4];
  const float* Wo     = (const float*)d_in[5];
  const float* ln1g   = (const float*)d_in[6];
  const float* ln1b   = (const float*)d_in[7];
  const float* ln2g   = (const float*)d_in[8];
  const float* ln2b   = (const float*)d_in[9];
  const float* fc1w   = (const float*)d_in[10];
  const float* fc1b   = (const float*)d_in[11];
  const float* fc2w   = (const float*)d_in[12];
  const float* fc2b   = (const float*)d_in[13];
  float* out = (float*)d_out;

  char* p = (char*)d_ws;
  auto alloc = [&](size_t bytes) { char* r = p; p += (bytes + 255) & ~(size_t)255; return r; };
  bf16*  Wb_w  = (bf16*)alloc(589824ull * 2);
  bf16*  Wb_v  = (bf16*)alloc(5898240ull * 2);
  bf16*  Wb_o  = (bf16*)alloc(5898240ull * 2);
  bf16*  Wb_f1 = (bf16*)alloc(2359296ull * 2);
  bf16*  Wb_f2 = (bf16*)alloc(2359296ull * 2);
  bf16*  Xb    = (bf16*)alloc(3145728ull * 2);
  float* PEf   = (float*)alloc(196608ull * 4);
  float* T     = (float*)alloc(3145728ull * 4);
  bf16*  SN    = (bf16*)alloc(3145728ull * 2);   // LN1 out; reused as LN2R out
  float* V     = (float*)alloc(3145728ull * 4);  // V; reused as S1
  bf16*  Cb    = (bf16*)alloc(3145728ull * 2);
  bf16*  H     = (bf16*)alloc(12582912ull * 2);
  float* Ps    = (float*)alloc(196608ull * 4);

  auto cvt = [&](const float* src, bf16* dst, int n) {
    int n4 = n / 4;
    f32_to_bf16_k<<<(n4 + 255) / 256, 256, 0, stream>>>(src, dst, n4);
  };
  cvt(x, Xb, 3145728);
  cvt(weight, Wb_w, 589824);
  cvt(Wv, Wb_v, 5898240);
  cvt(Wo, Wb_o, 5898240);
  cvt(fc1w, Wb_f1, 2359296);
  cvt(fc2w, Wb_f2, 2359296);
  pe_kernel<<<384, 256, 0, stream>>>(PEf);

  // T0 = x @ weight^T + PE
  gemm_bt<64, 64, EPI_PE><<<dim3(64, 12), 256, 0, stream>>>(Xb, Wb_w, T, nullptr, PEf, 768, 768);

  for (int a = 0; a < 10; ++a) {
    ln_kernel<0><<<4096, 256, 0, stream>>>(T, ln1g, ln1b, SN);
    gemm_bt<64, 64, EPI_F32><<<dim3(64, 12), 256, 0, stream>>>(SN, Wb_v + (size_t)a * 589824, V, nullptr, nullptr, 768, 768);
    scan_partial<<<dim3(16, 16, 3), 256, 0, stream>>>(V, Ps);
    scan_final<<<dim3(16, 16, 3), 256, 0, stream>>>(V, Ps, Cb);
    // S1 = C @ Wo^T + T   (S1 aliases V; V is dead after scan_final)
    gemm_bt<64, 64, EPI_RES><<<dim3(64, 12), 256, 0, stream>>>(Cb, Wb_o + (size_t)a * 589824, V, nullptr, T, 768, 768);
    ln_kernel<1><<<4096, 256, 0, stream>>>(V, ln2g, ln2b, SN);  // S2 = LN2(S1)+S1
    gemm_bt<64, 64, EPI_BIAS_GELU><<<dim3(64, 48), 256, 0, stream>>>(SN, Wb_f1, nullptr, H, fc1b, 768, 3072);
    float* dst = (a == 9) ? out : T;
    gemm_bt<64, 64, EPI_BIAS><<<dim3(64, 12), 256, 0, stream>>>(H, Wb_f2, dst, nullptr, fc2b, 3072, 768);
  }
  (void)in_sizes; (void)n_in; (void)out_size; (void)ws_size;
}

// Round 3
// 1383.805 us; speedup vs baseline: 1.3725x; 1.1029x over previous
//
#include <hip/hip_runtime.h>
#include <hip/hip_bf16.h>
#include <math.h>

// RTM identities:
//  - softmax over size-1 axis == 1  =>  q,k,Wq,Wk dead; newV == v
//  - token j restarts from s0[:,j]; only cumV couples tokens
//  - prefix-sum is linear: C_a = PS(LN1(T)) @ Wv^T  =>  fold Wv into Wo:
//       Wvo[a] = Wo[a] @ Wv[a]  (precomputed once)
//       S1 = PS(SN) @ Wvo[a]^T + T
// Per stage: scan(SN) -> sqGEMM(splitK2) -> reduce+res+LN2R -> fc1+GELU
//            -> fc2(splitK2) -> reduce+bias+LN1.
// All GEMMs 128x128 blocks, 64x64 wave tiles (8 ds_read : 16 MFMA per iter;
// R2's 64x64 blocks were LDS-read bound at 1:1).

using bf16   = __bf16;
using bf16x8 = __attribute__((ext_vector_type(8))) __bf16;
using f32x4  = __attribute__((ext_vector_type(4))) float;

#define DEV __device__ __forceinline__

DEV void gload16(const bf16* g, bf16* l) {
  __builtin_amdgcn_global_load_lds(
      (const __attribute__((address_space(1))) unsigned int*)g,
      (__attribute__((address_space(3))) unsigned int*)l, 16, 0, 0);
}

// GELU with A&S 7.1.26 erf (abs err 1.5e-7; << bf16 rounding).
DEV float gelu_f(float x) {
  const float y  = x * 0.70710678118654752f;
  const float ay = fabsf(y);
  const float t  = __builtin_amdgcn_rcpf(__builtin_fmaf(0.3275911f, ay, 1.0f));
  float p = __builtin_fmaf(1.061405429f, t, -1.453152027f);
  p = __builtin_fmaf(p, t, 1.421413741f);
  p = __builtin_fmaf(p, t, -0.284496736f);
  p = __builtin_fmaf(p, t, 0.254829592f);
  p = p * t;
  const float e = __expf(-ay * ay);
  float er = __builtin_fmaf(-p, e, 1.0f);
  er = __builtin_copysignf(er, y);
  return 0.5f * x * (1.0f + er);
}

enum { EPI_PART = 0, EPI_GELU = 1, EPI_B16 = 2 };

// C[128x128 tile] = A[M,K(+z*aZ)] @ B[N,K(+z*bZ)]^T over k in [z*kZ, z*kZ+klen).
// EPI_PART: fp32 partial -> outF + z*oZ.  EPI_GELU: bf16 gelu(v+bias) -> outB.
// EPI_B16: bf16 -> outB + z*oZ (batched weight-product).
template <int EPI>
__global__ __launch_bounds__(256) void gemm128(
    const bf16* __restrict__ A, const bf16* __restrict__ B,
    float* __restrict__ outF, bf16* __restrict__ outB,
    const float* __restrict__ aux, int K, int N,
    int kZ, int klen, size_t aZ, size_t bZ, size_t oZ)
{
  __shared__ bf16 As[128 * 32];
  __shared__ bf16 Bs[128 * 32];
  const int z = blockIdx.z;
  A += (size_t)z * aZ;
  B += (size_t)z * bZ;
  const int kbeg = z * kZ;
  const int tid  = threadIdx.x;
  const int lane = tid & 63, wave = tid >> 6;
  const int m0 = blockIdx.x * 128, n0 = blockIdx.y * 128;

  const bf16* aG0 = A + (size_t)(m0 + (tid >> 2)) * K + (tid & 3) * 8 + kbeg;
  const bf16* aG1 = aG0 + (size_t)64 * K;
  const bf16* bG0 = B + (size_t)(n0 + (tid >> 2)) * K + (tid & 3) * 8 + kbeg;
  const bf16* bG1 = bG0 + (size_t)64 * K;
  bf16* aL0 = &As[tid * 8];
  bf16* aL1 = &As[2048 + tid * 8];
  bf16* bL0 = &Bs[tid * 8];
  bf16* bL1 = &Bs[2048 + tid * 8];

  const int wr = (wave & 1) * 64, wc = (wave >> 1) * 64;
  const int lr = lane & 15, kb = lane >> 4;
  const bf16* apL = &As[(wr + lr) * 32 + kb * 8];
  const bf16* bpL = &Bs[(wc + lr) * 32 + kb * 8];

  f32x4 acc[4][4] = {};

  for (int k0 = 0; k0 < klen; k0 += 32) {
    gload16(aG0 + k0, aL0);
    gload16(aG1 + k0, aL1);
    gload16(bG0 + k0, bL0);
    gload16(bG1 + k0, bL1);
    __syncthreads();
    bf16x8 af[4], bfv[4];
#pragma unroll
    for (int t = 0; t < 4; ++t) af[t] = *(const bf16x8*)(apL + t * 512);
#pragma unroll
    for (int t = 0; t < 4; ++t) bfv[t] = *(const bf16x8*)(bpL + t * 512);
#pragma unroll
    for (int mt = 0; mt < 4; ++mt)
#pragma unroll
      for (int nt = 0; nt < 4; ++nt)
        acc[mt][nt] = __builtin_amdgcn_mfma_f32_16x16x32_bf16(af[mt], bfv[nt], acc[mt][nt], 0, 0, 0);
    __syncthreads();
  }

  // C/D layout: col = lane&15, row = (lane>>4)*4 + reg  [verified m89/m91]
  const int row0 = m0 + wr + (lane >> 4) * 4;
  const int col0 = n0 + wc + lr;
  float* oF = (EPI == EPI_PART) ? outF + (size_t)z * oZ : nullptr;
  bf16*  oB = (EPI == EPI_B16)  ? outB + (size_t)z * oZ : outB;
#pragma unroll
  for (int mt = 0; mt < 4; ++mt) {
#pragma unroll
    for (int nt = 0; nt < 4; ++nt) {
      const int col = col0 + nt * 16;
      float bias = 0.f;
      if (EPI == EPI_GELU) bias = aux[col];
#pragma unroll
      for (int r = 0; r < 4; ++r) {
        const int row = row0 + mt * 16 + r;
        float v = acc[mt][nt][r];
        if (EPI == EPI_PART) {
          oF[(size_t)row * N + col] = v;
        } else if (EPI == EPI_GELU) {
          oB[(size_t)row * N + col] = (bf16)gelu_f(v + bias);
        } else {
          oB[(size_t)row * N + col] = (bf16)v;
        }
      }
    }
  }
}

// One 768-row per block; sums NP split-K partials, adds per-MODE term, LN-fuses.
// MODE 0: s = Σp + PE[row&255]; T=s; SN = LN1(s)          (T0 / initial)
// MODE 1: s = Σp + add[row]   ; SN = LN2(s)+s             (square GEMM + residual)
// MODE 2: s = Σp + bias       ; T=s; SN = LN1(s)          (fc2, stages 0..8)
// MODE 3: s = Σp + bias       ; T=s (fp32 out only)       (fc2, last stage)
template <int NP, int MODE>
__global__ __launch_bounds__(256) void reduce_ln(
    const float* __restrict__ P, size_t pZ,
    const float* __restrict__ add, const float* __restrict__ g,
    const float* __restrict__ b, float* __restrict__ Tout,
    bf16* __restrict__ SNout)
{
  const int row = blockIdx.x, t = threadIdx.x;
  float v[3];
#pragma unroll
  for (int c = 0; c < 3; ++c) {
    const int col = t + c * 256;
    float s = P[(size_t)row * 768 + col];
#pragma unroll
    for (int p = 1; p < NP; ++p) s += P[(size_t)p * pZ + (size_t)row * 768 + col];
    if (MODE == 0) s += add[(row & 255) * 768 + col];
    if (MODE == 1) s += add[(size_t)row * 768 + col];
    if (MODE == 2 || MODE == 3) s += add[col];
    v[c] = s;
  }
  if (MODE != 1) {
#pragma unroll
    for (int c = 0; c < 3; ++c) Tout[(size_t)row * 768 + t + c * 256] = v[c];
  }
  if (MODE == 3) return;

  __shared__ float red[8];
  float s = v[0] + v[1] + v[2];
#pragma unroll
  for (int o = 32; o >= 1; o >>= 1) s += __shfl_down(s, o);
  if ((t & 63) == 0) red[t >> 6] = s;
  __syncthreads();
  const float mu = (red[0] + red[1] + red[2] + red[3]) * (1.f / 768.f);
  const float d0 = v[0] - mu, d1 = v[1] - mu, d2 = v[2] - mu;
  float q = d0 * d0 + d1 * d1 + d2 * d2;
#pragma unroll
  for (int o = 32; o >= 1; o >>= 1) q += __shfl_down(q, o);
  if ((t & 63) == 0) red[4 + (t >> 6)] = q;
  __syncthreads();
  const float var = (red[4] + red[5] + red[6] + red[7]) * (1.f / 768.f);
  const float rs = rsqrtf(var + 1e-5f);
  float y0 = d0 * rs * g[t] + b[t];
  float y1 = d1 * rs * g[t + 256] + b[t + 256];
  float y2 = d2 * rs * g[t + 512] + b[t + 512];
  if (MODE == 1) { y0 += v[0]; y1 += v[1]; y2 += v[2]; }
  bf16* o = SNout + (size_t)row * 768;
  o[t] = (bf16)y0; o[t + 256] = (bf16)y1; o[t + 512] = (bf16)y2;
}

// Exclusive prefix over token axis j (256 tokens) of SN[n,j,d], bf16 io.
__global__ __launch_bounds__(256) void scan_partial_b(
    const bf16* __restrict__ SN, float* __restrict__ Ps)
{
  const int n = blockIdx.x, ch = blockIdx.y, d = blockIdx.z * 256 + threadIdx.x;
  const bf16* base = SN + ((size_t)(n * 256 + ch * 16)) * 768 + d;
  float s = 0.f;
#pragma unroll
  for (int j = 0; j < 16; ++j) s += (float)base[(size_t)j * 768];
  Ps[(size_t)(n * 16 + ch) * 768 + d] = s;
}

__global__ __launch_bounds__(256) void scan_final_b(
    const bf16* __restrict__ SN, const float* __restrict__ Ps,
    bf16* __restrict__ PSb)
{
  const int n = blockIdx.x, ch = blockIdx.y, d = blockIdx.z * 256 + threadIdx.x;
  float run = 0.f;
  for (int c = 0; c < ch; ++c) run += Ps[(size_t)(n * 16 + c) * 768 + d];
  const bf16* vb = SN + ((size_t)(n * 256 + ch * 16)) * 768 + d;
  bf16* ob = PSb + ((size_t)(n * 256 + ch * 16)) * 768 + d;
#pragma unroll
  for (int j = 0; j < 16; ++j) {
    ob[(size_t)j * 768] = (bf16)run;
    run += (float)vb[(size_t)j * 768];
  }
}

// WvT[a][n][k] = (bf16)Wv[a][k][n]; 64x64 tiles via LDS (65-float stride).
__global__ __launch_bounds__(256) void transpose_wv(
    const float* __restrict__ Wv, bf16* __restrict__ WvT)
{
  __shared__ float tile[64][65];
  const int a = blockIdx.z, k0 = blockIdx.x * 64, n0 = blockIdx.y * 64;
  const int c = threadIdx.x & 63, r4 = threadIdx.x >> 6;
  const float* src = Wv + (size_t)a * 589824;
  bf16* dst = WvT + (size_t)a * 589824;
#pragma unroll
  for (int i = 0; i < 16; ++i)
    tile[r4 + i * 4][c] = src[(size_t)(k0 + r4 + i * 4) * 768 + n0 + c];
  __syncthreads();
#pragma unroll
  for (int i = 0; i < 16; ++i) {
    const int n = r4 + i * 4;
    dst[(size_t)(n0 + n) * 768 + k0 + c] = (bf16)tile[c][n];
  }
}

__global__ __launch_bounds__(256) void f32_to_bf16_k(
    const float* __restrict__ in, bf16* __restrict__ out, int n4)
{
  const int i = blockIdx.x * 256 + threadIdx.x;
  if (i >= n4) return;
  const float4 v = ((const float4*)in)[i];
  bf16 h[4] = {(bf16)v.x, (bf16)v.y, (bf16)v.z, (bf16)v.w};
  *(uint2*)(out + 4 * (size_t)i) = *(uint2*)h;
}

// pe[j, 2p] = sin(j / 10000^(4p/768)),  pe[j, 2p+1] = cos(...)
__global__ __launch_bounds__(256) void pe_kernel(float* __restrict__ PE)
{
  const int id = blockIdx.x * 256 + threadIdx.x;  // 256*384 total
  const int j = id / 384, p = id % 384;
  const double ang = (double)j * pow(10000.0, -4.0 * (double)p / 768.0);
  PE[(size_t)j * 768 + 2 * p]     = (float)sin(ang);
  PE[(size_t)j * 768 + 2 * p + 1] = (float)cos(ang);
}

extern "C" void kernel_launch(void* const* d_in, const int* in_sizes, int n_in,
                              void* d_out, int out_size, void* d_ws, size_t ws_size,
                              hipStream_t stream)
{
  const float* x      = (const float*)d_in[0];
  const float* weight = (const float*)d_in[1];
  const float* Wv     = (const float*)d_in[4];
  const float* Wo     = (const float*)d_in[5];
  const float* ln1g   = (const float*)d_in[6];
  const float* ln1b   = (const float*)d_in[7];
  const float* ln2g   = (const float*)d_in[8];
  const float* ln2b   = (const float*)d_in[9];
  const float* fc1w   = (const float*)d_in[10];
  const float* fc1b   = (const float*)d_in[11];
  const float* fc2w   = (const float*)d_in[12];
  const float* fc2b   = (const float*)d_in[13];
  float* out = (float*)d_out;

  char* p = (char*)d_ws;
  auto alloc = [&](size_t bytes) { char* r = p; p += (bytes + 255) & ~(size_t)255; return r; };
  bf16*  Wb_w  = (bf16*)alloc(589824ull * 2);
  bf16*  Wb_o  = (bf16*)alloc(5898240ull * 2);
  bf16*  WvT   = (bf16*)alloc(5898240ull * 2);
  bf16*  Wvo   = (bf16*)alloc(5898240ull * 2);
  bf16*  Wb_f1 = (bf16*)alloc(2359296ull * 2);
  bf16*  Wb_f2 = (bf16*)alloc(2359296ull * 2);
  bf16*  Xb    = (bf16*)alloc(3145728ull * 2);
  float* PEf   = (float*)alloc(196608ull * 4);
  float* T     = (float*)alloc(3145728ull * 4);
  bf16*  SN    = (bf16*)alloc(3145728ull * 2);
  bf16*  PSb   = (bf16*)alloc(3145728ull * 2);
  bf16*  H     = (bf16*)alloc(12582912ull * 2);
  float* Ps    = (float*)alloc(196608ull * 4);
  float* Part  = (float*)alloc(2ull * 3145728ull * 4);

  auto cvt = [&](const float* src, bf16* dst, int n) {
    int n4 = n / 4;
    f32_to_bf16_k<<<(n4 + 255) / 256, 256, 0, stream>>>(src, dst, n4);
  };
  cvt(x, Xb, 3145728);
  cvt(weight, Wb_w, 589824);
  cvt(Wo, Wb_o, 5898240);
  cvt(fc1w, Wb_f1, 2359296);
  cvt(fc2w, Wb_f2, 2359296);
  transpose_wv<<<dim3(12, 12, 10), 256, 0, stream>>>(Wv, WvT);
  pe_kernel<<<384, 256, 0, stream>>>(PEf);

  // Wvo[a] = Wo[a] @ Wv[a]  (A = Wo[a][m,t], B = WvT[a][k,t], batched over z)
  gemm128<EPI_B16><<<dim3(6, 6, 10), 256, 0, stream>>>(
      Wb_o, WvT, nullptr, Wvo, nullptr, 768, 768, 0, 768, 589824, 589824, 589824);

  // T0 = x @ weight^T + PE (split-K x2), fused LN1
  gemm128<EPI_PART><<<dim3(32, 6, 2), 256, 0, stream>>>(
      Xb, Wb_w, Part, nullptr, nullptr, 768, 768, 384, 384, 0, 0, 3145728);
  reduce_ln<2, 0><<<4096, 256, 0, stream>>>(Part, 3145728, PEf, ln1g, ln1b, T, SN);

  for (int a = 0; a < 10; ++a) {
    scan_partial_b<<<dim3(16, 16, 3), 256, 0, stream>>>(SN, Ps);
    scan_final_b<<<dim3(16, 16, 3), 256, 0, stream>>>(SN, Ps, PSb);
    // S1 partials = PS @ Wvo[a]^T  (split-K x2)
    gemm128<EPI_PART><<<dim3(32, 6, 2), 256, 0, stream>>>(
        PSb, Wvo + (size_t)a * 589824, Part, nullptr, nullptr, 768, 768, 384, 384, 0, 0, 3145728);
    reduce_ln<2, 1><<<4096, 256, 0, stream>>>(Part, 3145728, T, ln2g, ln2b, nullptr, SN);
    gemm128<EPI_GELU><<<dim3(32, 24, 1), 256, 0, stream>>>(
        SN, Wb_f1, nullptr, H, fc1b, 768, 3072, 0, 768, 0, 0, 0);
    gemm128<EPI_PART><<<dim3(32, 6, 2), 256, 0, stream>>>(
        H, Wb_f2, Part, nullptr, nullptr, 3072, 768, 1536, 1536, 0, 0, 3145728);
    if (a < 9)
      reduce_ln<2, 2><<<4096, 256, 0, stream>>>(Part, 3145728, fc2b, ln1g, ln1b, T, SN);
    else
      reduce_ln<2, 3><<<4096, 256, 0, stream>>>(Part, 3145728, fc2b, nullptr, nullptr, out, nullptr);
  }
  (void)in_sizes; (void)n_in; (void)out_size; (void)ws_size;
}

// Round 4
// 1252.732 us; speedup vs baseline: 1.5161x; 1.1046x over previous
//
#include <hip/hip_runtime.h>
#include <hip/hip_bf16.h>
#include <math.h>

// RTM identities:
//  - softmax over size-1 axis == 1  =>  q,k,Wq,Wk dead; newV == v
//  - token j restarts from s0[:,j]; only cumV couples tokens
//  - prefix-sum linear => fold Wv into Wo: Wvo[a] = Wo[a] @ Wv[a] (once);
//       S1 = PS(LN1(T)) @ Wvo[a]^T + T
// R4 GEMM core: XOR-swizzled LDS (kills the 8-way b128 bank conflict measured
// as 2.36e6 SQ_LDS_BANK_CONFLICT/dispatch in R3), double-buffered LDS with
// ONE barrier per K-iter (prefetch overlaps MFMA instead of full vmcnt(0)
// drain), 128x64 tiles for N=768 GEMMs so every grid is 768 blocks (3/CU).

using bf16   = __bf16;
using bf16x8 = __attribute__((ext_vector_type(8))) __bf16;
using f32x4  = __attribute__((ext_vector_type(4))) float;

#define DEV __device__ __forceinline__

DEV void gload16(const bf16* g, bf16* l) {
  __builtin_amdgcn_global_load_lds(
      (const __attribute__((address_space(1))) unsigned int*)g,
      (__attribute__((address_space(3))) unsigned int*)l, 16, 0, 0);
}

// GELU with A&S 7.1.26 erf (abs err 1.5e-7; << bf16 rounding).
DEV float gelu_f(float x) {
  const float y  = x * 0.70710678118654752f;
  const float ay = fabsf(y);
  const float t  = __builtin_amdgcn_rcpf(__builtin_fmaf(0.3275911f, ay, 1.0f));
  float p = __builtin_fmaf(1.061405429f, t, -1.453152027f);
  p = __builtin_fmaf(p, t, 1.421413741f);
  p = __builtin_fmaf(p, t, -0.284496736f);
  p = __builtin_fmaf(p, t, 0.254829592f);
  p = p * t;
  const float e = __expf(-ay * ay);
  float er = __builtin_fmaf(-p, e, 1.0f);
  er = __builtin_copysignf(er, y);
  return 0.5f * x * (1.0f + er);
}

enum { EPI_PART = 0, EPI_GELU = 1, EPI_B16 = 2 };

// C[128 x BN tile] = A[M,K(+z*aZ)] @ B[N,K(+z*bZ)]^T over k in [z*kZ, z*kZ+klen).
// LDS layout: row-major [row][4 slots of 8 bf16], slot s of row r holds global
// chunk kq = (s - (r>>1)) & 3  (xor/rotate swizzle -> 2-way bank floor).
template <int BN, int EPI>
__global__ __launch_bounds__(256) void gemm_k(
    const bf16* __restrict__ A, const bf16* __restrict__ B,
    float* __restrict__ outF, bf16* __restrict__ outB,
    const float* __restrict__ aux, int K, int N,
    int kZ, int klen, size_t aZ, size_t bZ, size_t oZ)
{
  constexpr int ABUF = 128 * 32;
  constexpr int BBUF = BN * 32;
  __shared__ bf16 As[2 * ABUF];
  __shared__ bf16 Bs[2 * BBUF];
  const int z = blockIdx.z;
  A += (size_t)z * aZ;
  B += (size_t)z * bZ;
  const int kbeg = z * kZ;
  const int tid  = threadIdx.x;
  const int lane = tid & 63, wave = tid >> 6;
  const int m0 = blockIdx.x * 128, n0 = blockIdx.y * BN;

  // Staging: thread tid covers row r = tid>>2, physical slot tid&3.
  // Global chunk for that slot: kq = ((tid&3) - (r>>1)) & 3 — a permutation
  // within one aligned 64B line, so coalescing is preserved.
  const int r  = tid >> 2;
  const int kq = ((tid & 3) - (tid >> 3)) & 3;
  const bf16* aG0 = A + (size_t)(m0 + r) * K + kq * 8 + kbeg;
  const bf16* aG1 = aG0 + (size_t)64 * K;
  const bf16* bG0 = B + (size_t)(n0 + r) * K + kq * 8 + kbeg;
  const bf16* bG1 = bG0 + (size_t)64 * K;   // used only for BN==128

  const int wr = (wave & 1) * 64, wc = (wave >> 1) * (BN / 2);
  const int lr = lane & 15, kb = lane >> 4;
  const int swz  = ((kb + (lr >> 1)) & 3) * 8;
  const int aOff = (wr + lr) * 32 + swz;
  const int bOff = (wc + lr) * 32 + swz;

  constexpr int MT = 4, NT = BN / 32;
  f32x4 acc[MT][NT] = {};
  const int iters = klen >> 5;

  auto stage = [&](int p, int k0) {
    bf16* aD = &As[p * ABUF + tid * 8];
    gload16(aG0 + k0, aD);
    gload16(aG1 + k0, aD + 2048);
    bf16* bD = &Bs[p * BBUF + tid * 8];
    gload16(bG0 + k0, bD);
    if (BN == 128) gload16(bG1 + k0, bD + 2048);
  };

  stage(0, 0);
  for (int it = 0; it < iters; ++it) {
    __syncthreads();                       // drains vmcnt (cur tile arrived) + lgkm
    if (it + 1 < iters) stage((it + 1) & 1, (it + 1) * 32);  // overlaps MFMA below
    const int pa = (it & 1) * ABUF, pb = (it & 1) * BBUF;
    bf16x8 af[MT], bfv[NT];
#pragma unroll
    for (int t = 0; t < MT; ++t) af[t] = *(const bf16x8*)&As[pa + aOff + t * 512];
#pragma unroll
    for (int t = 0; t < NT; ++t) bfv[t] = *(const bf16x8*)&Bs[pb + bOff + t * 512];
#pragma unroll
    for (int mt = 0; mt < MT; ++mt)
#pragma unroll
      for (int nt = 0; nt < NT; ++nt)
        acc[mt][nt] = __builtin_amdgcn_mfma_f32_16x16x32_bf16(af[mt], bfv[nt], acc[mt][nt], 0, 0, 0);
  }

  // C/D layout: col = lane&15, row = (lane>>4)*4 + reg  [verified m89/m91]
  const int row0 = m0 + wr + (lane >> 4) * 4;
  const int col0 = n0 + wc + lr;
  float* oF = (EPI == EPI_PART) ? outF + (size_t)z * oZ : nullptr;
  bf16*  oB = (EPI == EPI_B16)  ? outB + (size_t)z * oZ : outB;
#pragma unroll
  for (int mt = 0; mt < MT; ++mt) {
#pragma unroll
    for (int nt = 0; nt < NT; ++nt) {
      const int col = col0 + nt * 16;
      float bias = 0.f;
      if (EPI == EPI_GELU) bias = aux[col];
#pragma unroll
      for (int rg = 0; rg < 4; ++rg) {
        const int row = row0 + mt * 16 + rg;
        float v = acc[mt][nt][rg];
        if (EPI == EPI_PART) {
          oF[(size_t)row * N + col] = v;
        } else if (EPI == EPI_GELU) {
          oB[(size_t)row * N + col] = (bf16)gelu_f(v + bias);
        } else {
          oB[(size_t)row * N + col] = (bf16)v;
        }
      }
    }
  }
}

// One 768-row per block; sums NP split-K partials, adds per-MODE term, LN-fuses.
// MODE 0: s = Σp + PE[row&255]; T=s; SN = LN1(s)
// MODE 1: s = Σp + add[row]   ; SN = LN2(s)+s
// MODE 2: s = Σp + bias       ; T=s; SN = LN1(s)
// MODE 3: s = Σp + bias       ; T=s (fp32 out only, last stage)
template <int NP, int MODE>
__global__ __launch_bounds__(256) void reduce_ln(
    const float* __restrict__ P, size_t pZ,
    const float* __restrict__ add, const float* __restrict__ g,
    const float* __restrict__ b, float* __restrict__ Tout,
    bf16* __restrict__ SNout)
{
  const int row = blockIdx.x, t = threadIdx.x;
  float v[3];
#pragma unroll
  for (int c = 0; c < 3; ++c) {
    const int col = t + c * 256;
    float s = P[(size_t)row * 768 + col];
#pragma unroll
    for (int p = 1; p < NP; ++p) s += P[(size_t)p * pZ + (size_t)row * 768 + col];
    if (MODE == 0) s += add[(row & 255) * 768 + col];
    if (MODE == 1) s += add[(size_t)row * 768 + col];
    if (MODE == 2 || MODE == 3) s += add[col];
    v[c] = s;
  }
  if (MODE != 1) {
#pragma unroll
    for (int c = 0; c < 3; ++c) Tout[(size_t)row * 768 + t + c * 256] = v[c];
  }
  if (MODE == 3) return;

  __shared__ float red[8];
  float s = v[0] + v[1] + v[2];
#pragma unroll
  for (int o = 32; o >= 1; o >>= 1) s += __shfl_down(s, o);
  if ((t & 63) == 0) red[t >> 6] = s;
  __syncthreads();
  const float mu = (red[0] + red[1] + red[2] + red[3]) * (1.f / 768.f);
  const float d0 = v[0] - mu, d1 = v[1] - mu, d2 = v[2] - mu;
  float q = d0 * d0 + d1 * d1 + d2 * d2;
#pragma unroll
  for (int o = 32; o >= 1; o >>= 1) q += __shfl_down(q, o);
  if ((t & 63) == 0) red[4 + (t >> 6)] = q;
  __syncthreads();
  const float var = (red[4] + red[5] + red[6] + red[7]) * (1.f / 768.f);
  const float rs = rsqrtf(var + 1e-5f);
  float y0 = d0 * rs * g[t] + b[t];
  float y1 = d1 * rs * g[t + 256] + b[t + 256];
  float y2 = d2 * rs * g[t + 512] + b[t + 512];
  if (MODE == 1) { y0 += v[0]; y1 += v[1]; y2 += v[2]; }
  bf16* o = SNout + (size_t)row * 768;
  o[t] = (bf16)y0; o[t + 256] = (bf16)y1; o[t + 512] = (bf16)y2;
}

// Exclusive prefix over token axis j (256 tokens) of SN[n,j,d], bf16 io.
__global__ __launch_bounds__(256) void scan_partial_b(
    const bf16* __restrict__ SN, float* __restrict__ Ps)
{
  const int n = blockIdx.x, ch = blockIdx.y, d = blockIdx.z * 256 + threadIdx.x;
  const bf16* base = SN + ((size_t)(n * 256 + ch * 16)) * 768 + d;
  float s = 0.f;
#pragma unroll
  for (int j = 0; j < 16; ++j) s += (float)base[(size_t)j * 768];
  Ps[(size_t)(n * 16 + ch) * 768 + d] = s;
}

__global__ __launch_bounds__(256) void scan_final_b(
    const bf16* __restrict__ SN, const float* __restrict__ Ps,
    bf16* __restrict__ PSb)
{
  const int n = blockIdx.x, ch = blockIdx.y, d = blockIdx.z * 256 + threadIdx.x;
  float run = 0.f;
  for (int c = 0; c < ch; ++c) run += Ps[(size_t)(n * 16 + c) * 768 + d];
  const bf16* vb = SN + ((size_t)(n * 256 + ch * 16)) * 768 + d;
  bf16* ob = PSb + ((size_t)(n * 256 + ch * 16)) * 768 + d;
#pragma unroll
  for (int j = 0; j < 16; ++j) {
    ob[(size_t)j * 768] = (bf16)run;
    run += (float)vb[(size_t)j * 768];
  }
}

// WvT[a][n][k] = (bf16)Wv[a][k][n]; 64x64 tiles via LDS (65-float stride).
__global__ __launch_bounds__(256) void transpose_wv(
    const float* __restrict__ Wv, bf16* __restrict__ WvT)
{
  __shared__ float tile[64][65];
  const int a = blockIdx.z, k0 = blockIdx.x * 64, n0 = blockIdx.y * 64;
  const int c = threadIdx.x & 63, r4 = threadIdx.x >> 6;
  const float* src = Wv + (size_t)a * 589824;
  bf16* dst = WvT + (size_t)a * 589824;
#pragma unroll
  for (int i = 0; i < 16; ++i)
    tile[r4 + i * 4][c] = src[(size_t)(k0 + r4 + i * 4) * 768 + n0 + c];
  __syncthreads();
#pragma unroll
  for (int i = 0; i < 16; ++i) {
    const int n = r4 + i * 4;
    dst[(size_t)(n0 + n) * 768 + k0 + c] = (bf16)tile[c][n];
  }
}

__global__ __launch_bounds__(256) void f32_to_bf16_k(
    const float* __restrict__ in, bf16* __restrict__ out, int n4)
{
  const int i = blockIdx.x * 256 + threadIdx.x;
  if (i >= n4) return;
  const float4 v = ((const float4*)in)[i];
  bf16 h[4] = {(bf16)v.x, (bf16)v.y, (bf16)v.z, (bf16)v.w};
  *(uint2*)(out + 4 * (size_t)i) = *(uint2*)h;
}

// pe[j, 2p] = sin(j / 10000^(4p/768)),  pe[j, 2p+1] = cos(...)
__global__ __launch_bounds__(256) void pe_kernel(float* __restrict__ PE)
{
  const int id = blockIdx.x * 256 + threadIdx.x;  // 256*384 total
  const int j = id / 384, p = id % 384;
  const double ang = (double)j * pow(10000.0, -4.0 * (double)p / 768.0);
  PE[(size_t)j * 768 + 2 * p]     = (float)sin(ang);
  PE[(size_t)j * 768 + 2 * p + 1] = (float)cos(ang);
}

extern "C" void kernel_launch(void* const* d_in, const int* in_sizes, int n_in,
                              void* d_out, int out_size, void* d_ws, size_t ws_size,
                              hipStream_t stream)
{
  const float* x      = (const float*)d_in[0];
  const float* weight = (const float*)d_in[1];
  const float* Wv     = (const float*)d_in[4];
  const float* Wo     = (const float*)d_in[5];
  const float* ln1g   = (const float*)d_in[6];
  const float* ln1b   = (const float*)d_in[7];
  const float* ln2g   = (const float*)d_in[8];
  const float* ln2b   = (const float*)d_in[9];
  const float* fc1w   = (const float*)d_in[10];
  const float* fc1b   = (const float*)d_in[11];
  const float* fc2w   = (const float*)d_in[12];
  const float* fc2b   = (const float*)d_in[13];
  float* out = (float*)d_out;

  char* p = (char*)d_ws;
  auto alloc = [&](size_t bytes) { char* r = p; p += (bytes + 255) & ~(size_t)255; return r; };
  bf16*  Wb_w  = (bf16*)alloc(589824ull * 2);
  bf16*  Wb_o  = (bf16*)alloc(5898240ull * 2);
  bf16*  WvT   = (bf16*)alloc(5898240ull * 2);
  bf16*  Wvo   = (bf16*)alloc(5898240ull * 2);
  bf16*  Wb_f1 = (bf16*)alloc(2359296ull * 2);
  bf16*  Wb_f2 = (bf16*)alloc(2359296ull * 2);
  bf16*  Xb    = (bf16*)alloc(3145728ull * 2);
  float* PEf   = (float*)alloc(196608ull * 4);
  float* T     = (float*)alloc(3145728ull * 4);
  bf16*  SN    = (bf16*)alloc(3145728ull * 2);
  bf16*  PSb   = (bf16*)alloc(3145728ull * 2);
  bf16*  H     = (bf16*)alloc(12582912ull * 2);
  float* Ps    = (float*)alloc(196608ull * 4);
  float* Part  = (float*)alloc(2ull * 3145728ull * 4);

  auto cvt = [&](const float* src, bf16* dst, int n) {
    int n4 = n / 4;
    f32_to_bf16_k<<<(n4 + 255) / 256, 256, 0, stream>>>(src, dst, n4);
  };
  cvt(x, Xb, 3145728);
  cvt(weight, Wb_w, 589824);
  cvt(Wo, Wb_o, 5898240);
  cvt(fc1w, Wb_f1, 2359296);
  cvt(fc2w, Wb_f2, 2359296);
  transpose_wv<<<dim3(12, 12, 10), 256, 0, stream>>>(Wv, WvT);
  pe_kernel<<<384, 256, 0, stream>>>(PEf);

  // Wvo[a] = Wo[a] @ Wv[a]  (A = Wo[a][m,t], B = WvT[a][k,t], batched over z)
  gemm_k<128, EPI_B16><<<dim3(6, 6, 10), 256, 0, stream>>>(
      Wb_o, WvT, nullptr, Wvo, nullptr, 768, 768, 0, 768, 589824, 589824, 589824);

  // T0 = x @ weight^T + PE (split-K x2, 128x64 tiles), fused LN1
  gemm_k<64, EPI_PART><<<dim3(32, 12, 2), 256, 0, stream>>>(
      Xb, Wb_w, Part, nullptr, nullptr, 768, 768, 384, 384, 0, 0, 3145728);
  reduce_ln<2, 0><<<4096, 256, 0, stream>>>(Part, 3145728, PEf, ln1g, ln1b, T, SN);

  for (int a = 0; a < 10; ++a) {
    scan_partial_b<<<dim3(16, 16, 3), 256, 0, stream>>>(SN, Ps);
    scan_final_b<<<dim3(16, 16, 3), 256, 0, stream>>>(SN, Ps, PSb);
    // S1 partials = PS @ Wvo[a]^T  (split-K x2, 128x64 tiles)
    gemm_k<64, EPI_PART><<<dim3(32, 12, 2), 256, 0, stream>>>(
        PSb, Wvo + (size_t)a * 589824, Part, nullptr, nullptr, 768, 768, 384, 384, 0, 0, 3145728);
    reduce_ln<2, 1><<<4096, 256, 0, stream>>>(Part, 3145728, T, ln2g, ln2b, nullptr, SN);
    gemm_k<128, EPI_GELU><<<dim3(32, 24, 1), 256, 0, stream>>>(
        SN, Wb_f1, nullptr, H, fc1b, 768, 3072, 0, 768, 0, 0, 0);
    gemm_k<64, EPI_PART><<<dim3(32, 12, 2), 256, 0, stream>>>(
        H, Wb_f2, Part, nullptr, nullptr, 3072, 768, 1536, 1536, 0, 0, 3145728);
    if (a < 9)
      reduce_ln<2, 2><<<4096, 256, 0, stream>>>(Part, 3145728, fc2b, ln1g, ln1b, T, SN);
    else
      reduce_ln<2, 3><<<4096, 256, 0, stream>>>(Part, 3145728, fc2b, nullptr, nullptr, out, nullptr);
  }
  (void)in_sizes; (void)n_in; (void)out_size; (void)ws_size;
}